// Round 2
// baseline (1112.292 us; speedup 1.0000x reference)
//
#include <hip/hip_runtime.h>
#include <hip/hip_cooperative_groups.h>
#include <cstdint>
#include <cstddef>

namespace cg = cooperative_groups;

// Problem constants (from reference setup_inputs)
#define C_ 4
#define B_ 128
#define G_ 2048
#define S_ 32
#define L_ 3
#define NSTEP_ 3
#define GAMMA_ 0.01f
#define INVG_ 100.0f
#define CG_ (C_ * G_)                   // 8192 (c,g) pairs
#define NTASK_ (CG_ * 2)                // wave-tasks per gather step (2 b-halves)
#define NELEM_ ((size_t)C_ * G_ * B_)   // 1048576
#define PERC_ ((size_t)G_ * B_)         // 262144 (power of 2)

// ---------------------------------------------------------------------------
// Lazy-normalization bookkeeping: slots[k] holds float-bits of global maxes.
// slot 0: 0 (scale 1 for step 0); step k: m1 -> 2k+1, m2 -> 2k+2.
// All stored values are strictly positive -> uint bit-compare == float compare.
// ---------------------------------------------------------------------------

__device__ __forceinline__ float slot_scale(const uint32_t* slots, int i) {
  const float m = __uint_as_float(
      __hip_atomic_load(slots + i, __ATOMIC_RELAXED, __HIP_MEMORY_SCOPE_AGENT));
  return (m > 1.0f) ? (1.0f / m) : 1.0f;
}

__device__ __forceinline__ void block_max_to_slot(float tmax, uint32_t* slot,
                                                  uint32_t* smax) {
  __syncthreads();
  if (threadIdx.x == 0) *smax = 0u;
  __syncthreads();
  atomicMax(smax, __float_as_uint(tmax));
  __syncthreads();
  if (threadIdx.x == 0) atomicMax(slot, *smax);  // fire-and-forget, device scope
}

// x[B,G] -> Xt[G,B] tiled transpose (1 MB)
__device__ void dev_tin(const float* __restrict__ x, float* __restrict__ Xt,
                        float (*tile)[33]) {
  const int tx = threadIdx.x & 31, ty = threadIdx.x >> 5;
  const int NT = (G_ / 32) * (B_ / 32);  // 256 tiles
  for (int t = blockIdx.x; t < NT; t += gridDim.x) {
    const int g0 = (t % (G_ / 32)) * 32, b0 = (t / (G_ / 32)) * 32;
    __syncthreads();
    for (int i = ty; i < 32; i += 8)
      tile[i][tx] = x[(size_t)(b0 + i) * G_ + g0 + tx];  // tile[b][g]
    __syncthreads();
    for (int j = ty; j < 32; j += 8)
      Xt[(size_t)(g0 + j) * B_ + b0 + tx] = tile[tx][j];
  }
}

// gather + soft-OR over S. One wave-task = (cg, b-half). Indices loaded with
// 2 coalesced loads then broadcast via v_readlane (compile-time lanes) so the
// A-row loads are SGPR-base + lane voffset: zero per-load VALU address math.
// Fixed-offset logsumexp (values bounded in [0, ~1.04]): no max pass.
__device__ float dev_gather(const float* __restrict__ src, size_t cstride,
                            const int* __restrict__ Idx, float* __restrict__ Lb,
                            float s3INVG) {
  const int lane = threadIdx.x & 63;
  const int gwave = blockIdx.x * 4 + (threadIdx.x >> 6);
  const int nwav = gridDim.x * 4;
  float tmax = 0.0f;
  for (int task = gwave; task < NTASK_; task += nwav) {
    const int cg = task >> 1;
    const int half = task & 1;
    const int c = cg >> 11;  // cg / G_
    const int* ip = Idx + (size_t)cg * (S_ * L_);
    const int i0 = ip[lane];
    const int i1 = ip[64 + (lane & 31)];  // always in-bounds (95 max)
    const float* base = src + (size_t)c * cstride + half * 64 + lane;
    float acc0 = 0.0f, acc1 = 0.0f;
#pragma unroll
    for (int s = 0; s < S_; ++s) {
      const int k0 = 3 * s, k1 = 3 * s + 1, k2 = 3 * s + 2;
      const int e0 = (k0 < 64) ? __builtin_amdgcn_readlane(i0, k0)
                               : __builtin_amdgcn_readlane(i1, k0 - 64);
      const int e1 = (k1 < 64) ? __builtin_amdgcn_readlane(i0, k1)
                               : __builtin_amdgcn_readlane(i1, k1 - 64);
      const int e2 = (k2 < 64) ? __builtin_amdgcn_readlane(i0, k2)
                               : __builtin_amdgcn_readlane(i1, k2 - 64);
      const float v0 = base[(size_t)e0 * B_];
      const float v1 = base[(size_t)e1 * B_];
      const float v2 = base[(size_t)e2 * B_];
      const float p = (v0 * v1) * v2;                 // scale^3 folded into exp
      const float e = __expf(fmaf(p, s3INVG, -50.0f));
      if (s & 1) acc1 += e; else acc0 += e;           // break add chain
    }
    const float lse = 0.5f + GAMMA_ * __logf(acc0 + acc1);
    Lb[(size_t)cg * B_ + half * 64 + lane] = lse;
    tmax = fmaxf(tmax, lse);
  }
  return tmax;
}

// 2-way soft-OR: A = softor2(R_prev * sprev, lse1 * s1), elementwise
__device__ float dev_elem(int step, float* __restrict__ A,
                          const float* __restrict__ Xt,
                          const float* __restrict__ Lb, float sprevI,
                          float s1I) {
  float tmax = 0.0f;
  const size_t stride = (size_t)gridDim.x * 256;
  for (size_t i = (size_t)blockIdx.x * 256 + threadIdx.x; i < NELEM_;
       i += stride) {
    const float Rp = (step == 0) ? Xt[i & (PERC_ - 1)] : A[i];
    const float ce = Lb[i];
    const float eR = __expf(fmaf(Rp, sprevI, -50.0f));
    const float eC = __expf(fmaf(ce, s1I, -50.0f));
    const float lse2 = 0.5f + GAMMA_ * __logf(eR + eC);
    A[i] = lse2;
    tmax = fmaxf(tmax, lse2);
  }
  return tmax;
}

// A[c,g,b] -> out[c,b,g] with final scale (tiled transpose)
__device__ void dev_out(const float* __restrict__ A, float* __restrict__ out,
                        float sc, float (*tile)[33]) {
  const int tx = threadIdx.x & 31, ty = threadIdx.x >> 5;
  const int TPC = (G_ / 32) * (B_ / 32);  // 256
  const int NT = C_ * TPC;                // 1024
  for (int t = blockIdx.x; t < NT; t += gridDim.x) {
    const int c = t / TPC, r = t % TPC;
    const int g0 = (r % (G_ / 32)) * 32, b0 = (r / (G_ / 32)) * 32;
    __syncthreads();
    for (int j = ty; j < 32; j += 8)
      tile[j][tx] = A[((size_t)c * G_ + g0 + j) * B_ + b0 + tx];  // tile[g][b]
    __syncthreads();
    for (int i = ty; i < 32; i += 8)
      out[((size_t)c * B_ + b0 + i) * G_ + g0 + tx] = tile[tx][i] * sc;
  }
}

// ---------------------------------------------------------------------------
// Fused cooperative kernel: init, [gather, elem] x3, out — one dispatch.
// ---------------------------------------------------------------------------
__global__ __launch_bounds__(256, 4) void k_fused(
    const float* __restrict__ x, const int* __restrict__ Idx,
    float* __restrict__ out, float* __restrict__ Xt, float* __restrict__ A,
    float* __restrict__ Lb, uint32_t* __restrict__ slots) {
  __shared__ float tile[32][33];
  __shared__ uint32_t smax;
  cg::grid_group g = cg::this_grid();

  if (blockIdx.x == 0 && threadIdx.x < 8)
    __hip_atomic_store(slots + threadIdx.x, 0u, __ATOMIC_RELAXED,
                       __HIP_MEMORY_SCOPE_AGENT);
  dev_tin(x, Xt, tile);
  __threadfence();
  g.sync();

  for (int step = 0; step < NSTEP_; ++step) {
    const float sprev = slot_scale(slots, 2 * step);
    const float s3 = sprev * sprev * sprev;
    float tmax = dev_gather(step == 0 ? Xt : A,
                            step == 0 ? (size_t)0 : PERC_, Idx, Lb,
                            s3 * INVG_);
    block_max_to_slot(tmax, slots + 2 * step + 1, &smax);
    __threadfence();
    g.sync();
    const float s1 = slot_scale(slots, 2 * step + 1);
    tmax = dev_elem(step, A, Xt, Lb, sprev * INVG_, s1 * INVG_);
    block_max_to_slot(tmax, slots + 2 * step + 2, &smax);
    __threadfence();
    g.sync();
  }
  const float m = __uint_as_float(__hip_atomic_load(
      slots + 2 * NSTEP_, __ATOMIC_RELAXED, __HIP_MEMORY_SCOPE_AGENT));
  dev_out(A, out, (m > 1.0f) ? 1.0f / m : 1.0f, tile);
}

// Fallback: same phases as separate launches (stream order = barrier)
__global__ __launch_bounds__(256, 4) void k_phase(
    const float* __restrict__ x, const int* __restrict__ Idx,
    float* __restrict__ out, float* __restrict__ Xt, float* __restrict__ A,
    float* __restrict__ Lb, uint32_t* __restrict__ slots, int phase,
    int step) {
  __shared__ float tile[32][33];
  __shared__ uint32_t smax;
  if (phase == 0) {
    if (blockIdx.x == 0 && threadIdx.x < 8)
      __hip_atomic_store(slots + threadIdx.x, 0u, __ATOMIC_RELAXED,
                         __HIP_MEMORY_SCOPE_AGENT);
    dev_tin(x, Xt, tile);
  } else if (phase == 1) {
    const float sprev = slot_scale(slots, 2 * step);
    const float s3 = sprev * sprev * sprev;
    float tmax = dev_gather(step == 0 ? Xt : A,
                            step == 0 ? (size_t)0 : PERC_, Idx, Lb,
                            s3 * INVG_);
    block_max_to_slot(tmax, slots + 2 * step + 1, &smax);
  } else if (phase == 2) {
    const float sprev = slot_scale(slots, 2 * step);
    const float s1 = slot_scale(slots, 2 * step + 1);
    float tmax = dev_elem(step, A, Xt, Lb, sprev * INVG_, s1 * INVG_);
    block_max_to_slot(tmax, slots + 2 * step + 2, &smax);
  } else {
    const float m = __uint_as_float(__hip_atomic_load(
        slots + 2 * NSTEP_, __ATOMIC_RELAXED, __HIP_MEMORY_SCOPE_AGENT));
    dev_out(A, out, (m > 1.0f) ? 1.0f / m : 1.0f, tile);
  }
}

extern "C" void kernel_launch(void* const* d_in, const int* in_sizes, int n_in,
                              void* d_out, int out_size, void* d_ws,
                              size_t ws_size, hipStream_t stream) {
  const float* x = (const float*)d_in[0];  // [B,G]
  const int* Idx = (const int*)d_in[1];    // [C,G,S,L]
  float* out = (float*)d_out;              // [C,B,G]

  char* ws = (char*)d_ws;
  uint32_t* slots = (uint32_t*)ws;                       // 7 scalar max slots
  float* Xt = (float*)(ws + 256);                        // [G,B]   1 MB
  float* A = (float*)(ws + 256 + PERC_ * 4);             // [C,G,B] 4 MB
  float* Lb = (float*)(ws + 256 + PERC_ * 4 + NELEM_ * 4);  // [C,G,B] 4 MB

  int nb = 0;
  hipError_t oe = hipOccupancyMaxActiveBlocksPerMultiprocessor(&nb, k_fused,
                                                               256, 0);
  int grid = (oe == hipSuccess && nb > 0) ? nb * 256 : 256;  // 256 CUs
  if (grid > 1024) grid = 1024;

  void* args[] = {(void*)&x, (void*)&Idx, (void*)&out, (void*)&Xt,
                  (void*)&A, (void*)&Lb,  (void*)&slots};
  hipError_t le = hipLaunchCooperativeKernel((const void*)k_fused, dim3(grid),
                                             dim3(256), args, 0, stream);
  if (le != hipSuccess) {
    k_phase<<<grid, 256, 0, stream>>>(x, Idx, out, Xt, A, Lb, slots, 0, 0);
    for (int s = 0; s < NSTEP_; ++s) {
      k_phase<<<grid, 256, 0, stream>>>(x, Idx, out, Xt, A, Lb, slots, 1, s);
      k_phase<<<grid, 256, 0, stream>>>(x, Idx, out, Xt, A, Lb, slots, 2, s);
    }
    k_phase<<<grid, 256, 0, stream>>>(x, Idx, out, Xt, A, Lb, slots, 3, 0);
  }
}

// Round 3
// 652.201 us; speedup vs baseline: 1.7054x; 1.7054x over previous
//
#include <hip/hip_runtime.h>
#include <cstdint>
#include <cstddef>

// Problem constants (from reference setup_inputs)
#define C_ 4
#define B_ 128
#define G_ 2048
#define S_ 32
#define L_ 3
#define NSTEP_ 3
#define GAMMA_ 0.01f
#define INVG_ 100.0f
#define CG_ (C_ * G_)                  // 8192 (c,g) pairs
#define NTASK_ (CG_ * 2)               // wave-tasks per gather (2 b-halves)
#define NELEM_ ((size_t)C_ * G_ * B_)  // 1048576
#define PERC_ ((size_t)G_ * B_)        // 262144 (power of 2)

// Lazy-normalization slots: slots[k] = float-bits of global maxes (all > 0 so
// uint bit-compare == float compare). slot 0 stays 0 (scale 1 for step 0);
// step k writes m1 -> 2k+1, m2 -> 2k+2. Stream order = cross-kernel barrier.

__device__ __forceinline__ float slot_scale(const uint32_t* slots, int i) {
  const float m = __uint_as_float(
      __hip_atomic_load(slots + i, __ATOMIC_RELAXED, __HIP_MEMORY_SCOPE_AGENT));
  return (m > 1.0f) ? (1.0f / m) : 1.0f;
}

// ---------------------------------------------------------------------------
// k_init: Xt[g,b] = x[b,g] (tiled transpose, both sides coalesced)
// ---------------------------------------------------------------------------
__global__ __launch_bounds__(256) void k_init(const float* __restrict__ x,
                                              float* __restrict__ Xt) {
  __shared__ float tile[32][33];
  const int g0 = blockIdx.x * 32, b0 = blockIdx.y * 32;
  const int tx = threadIdx.x;
  for (int i = threadIdx.y; i < 32; i += 8)
    tile[i][tx] = x[(size_t)(b0 + i) * G_ + g0 + tx];  // tile[b][g]
  __syncthreads();
  for (int j = threadIdx.y; j < 32; j += 8)
    Xt[(size_t)(g0 + j) * B_ + b0 + tx] = tile[tx][j];
}

// ---------------------------------------------------------------------------
// k_gather: one wave per (cg, b-half). Indices via 2 coalesced loads +
// v_readlane (compile-time lanes) -> SGPR-uniform row offsets -> A-row loads
// are saddr-form global_load with a constant lane voffset (no per-load VALU).
// Loads staged to register arrays (ILP), then fixed-offset logsumexp
// (valuations bounded in [0,~1.04] -> exponent in [-50,54], no max pass).
// ---------------------------------------------------------------------------
__global__ __launch_bounds__(256, 4) void k_gather(
    const float* __restrict__ src, size_t cstride, const int* __restrict__ Idx,
    float* __restrict__ Lb, uint32_t* __restrict__ slots, int prev_slot,
    int out_slot) {
  __shared__ uint32_t smax;
  if (threadIdx.x == 0) smax = 0u;
  __syncthreads();
  const int lane = threadIdx.x & 63;
  const int wid = threadIdx.x >> 6;
  const float sc = slot_scale(slots, prev_slot);
  const float s3I = sc * sc * sc * INVG_;  // fold scale^3 into exp argument
  float tmax = 0.0f;

  for (int task = blockIdx.x * 4 + wid; task < NTASK_; task += gridDim.x * 4) {
    const int cg = task >> 1;
    const int half = task & 1;
    const int c = cg >> 11;  // cg / G_
    const int* ip = Idx + (size_t)cg * (S_ * L_);
    const int i0 = ip[lane];
    const int i1 = ip[64 + (lane & 31)];  // k=64..95
    const float* base = src + (size_t)c * cstride + half * 64 + lane;

    float va[S_], vb[S_], vc[S_];
#pragma unroll
    for (int s = 0; s < S_; ++s) {
      const int k0 = 3 * s, k1 = 3 * s + 1, k2 = 3 * s + 2;
      const int e0 = (k0 < 64) ? __builtin_amdgcn_readlane(i0, k0)
                               : __builtin_amdgcn_readlane(i1, k0 - 64);
      const int e1 = (k1 < 64) ? __builtin_amdgcn_readlane(i0, k1)
                               : __builtin_amdgcn_readlane(i1, k1 - 64);
      const int e2 = (k2 < 64) ? __builtin_amdgcn_readlane(i0, k2)
                               : __builtin_amdgcn_readlane(i1, k2 - 64);
      va[s] = base[(size_t)e0 * B_];
      vb[s] = base[(size_t)e1 * B_];
      vc[s] = base[(size_t)e2 * B_];
    }
    float acc0 = 0.0f, acc1 = 0.0f;
#pragma unroll
    for (int s = 0; s < S_; ++s) {
      const float p = (va[s] * vb[s]) * vc[s];
      const float e = __expf(fmaf(p, s3I, -50.0f));
      if (s & 1) acc1 += e; else acc0 += e;  // split dependency chain
    }
    const float lse = 0.5f + GAMMA_ * __logf(acc0 + acc1);
    Lb[(size_t)cg * B_ + half * 64 + lane] = lse;
    tmax = fmaxf(tmax, lse);
  }
  atomicMax(&smax, __float_as_uint(tmax));
  __syncthreads();
  if (threadIdx.x == 0) atomicMax(slots + out_slot, smax);
}

// ---------------------------------------------------------------------------
// k_elem: A = softor2(R_prev * sprev, lse1 * s1), float4-vectorized,
// with global-max side computation.
// ---------------------------------------------------------------------------
__global__ __launch_bounds__(256) void k_elem(float* __restrict__ A,
                                              const float* __restrict__ Xt,
                                              const float* __restrict__ Lb,
                                              uint32_t* __restrict__ slots,
                                              int step, int prev_slot,
                                              int m1_slot, int out_slot) {
  __shared__ uint32_t smax;
  if (threadIdx.x == 0) smax = 0u;
  __syncthreads();
  const float spI = slot_scale(slots, prev_slot) * INVG_;
  const float s1I = slot_scale(slots, m1_slot) * INVG_;
  float tmax = 0.0f;
  const size_t n4 = NELEM_ / 4;
  const size_t stride = (size_t)gridDim.x * blockDim.x;
  float4* A4 = (float4*)A;
  const float4* X4 = (const float4*)Xt;
  const float4* L4 = (const float4*)Lb;
  for (size_t i = (size_t)blockIdx.x * blockDim.x + threadIdx.x; i < n4;
       i += stride) {
    const float4 R = (step == 0) ? X4[i & (PERC_ / 4 - 1)] : A4[i];
    const float4 ce = L4[i];
    float4 o;
    o.x = 0.5f + GAMMA_ * __logf(__expf(fmaf(R.x, spI, -50.0f)) +
                                 __expf(fmaf(ce.x, s1I, -50.0f)));
    o.y = 0.5f + GAMMA_ * __logf(__expf(fmaf(R.y, spI, -50.0f)) +
                                 __expf(fmaf(ce.y, s1I, -50.0f)));
    o.z = 0.5f + GAMMA_ * __logf(__expf(fmaf(R.z, spI, -50.0f)) +
                                 __expf(fmaf(ce.z, s1I, -50.0f)));
    o.w = 0.5f + GAMMA_ * __logf(__expf(fmaf(R.w, spI, -50.0f)) +
                                 __expf(fmaf(ce.w, s1I, -50.0f)));
    A4[i] = o;
    tmax = fmaxf(fmaxf(fmaxf(o.x, o.y), fmaxf(o.z, o.w)), tmax);
  }
  atomicMax(&smax, __float_as_uint(tmax));
  __syncthreads();
  if (threadIdx.x == 0) atomicMax(slots + out_slot, smax);
}

// ---------------------------------------------------------------------------
// k_out: out[c,b,g] = A[c,g,b] * final_scale (tiled transpose back)
// ---------------------------------------------------------------------------
__global__ __launch_bounds__(256) void k_out(const float* __restrict__ A,
                                             float* __restrict__ out,
                                             const uint32_t* __restrict__ slots,
                                             int mslot) {
  __shared__ float tile[32][33];
  const float sc = slot_scale(slots, mslot);
  const int g0 = blockIdx.x * 32, b0 = blockIdx.y * 32, c = blockIdx.z;
  const int tx = threadIdx.x;
  for (int j = threadIdx.y; j < 32; j += 8)
    tile[j][tx] = A[((size_t)c * G_ + g0 + j) * B_ + b0 + tx];  // tile[g][b]
  __syncthreads();
  for (int i = threadIdx.y; i < 32; i += 8)
    out[((size_t)c * B_ + b0 + i) * G_ + g0 + tx] = tile[tx][i] * sc;
}

extern "C" void kernel_launch(void* const* d_in, const int* in_sizes, int n_in,
                              void* d_out, int out_size, void* d_ws,
                              size_t ws_size, hipStream_t stream) {
  const float* x = (const float*)d_in[0];  // [B,G]
  const int* Idx = (const int*)d_in[1];    // [C,G,S,L]
  float* out = (float*)d_out;              // [C,B,G]

  char* ws = (char*)d_ws;
  uint32_t* slots = (uint32_t*)ws;                          // 7 max slots
  float* Xt = (float*)(ws + 256);                           // [G,B]   1 MB
  float* A = (float*)(ws + 256 + PERC_ * 4);                // [C,G,B] 4 MB
  float* Lb = (float*)(ws + 256 + PERC_ * 4 + NELEM_ * 4);  // [C,G,B] 4 MB

  hipMemsetAsync(slots, 0, 8 * sizeof(uint32_t), stream);

  dim3 tb(32, 8);
  k_init<<<dim3(G_ / 32, B_ / 32), tb, 0, stream>>>(x, Xt);

  for (int step = 0; step < NSTEP_; ++step) {
    const int prev = 2 * step;  // slot 0 == 0 -> scale 1 for step 0
    const int m1s = 2 * step + 1;
    const int m2s = 2 * step + 2;
    const float* src = (step == 0) ? Xt : A;
    const size_t cstride = (step == 0) ? (size_t)0 : PERC_;
    k_gather<<<4096, 256, 0, stream>>>(src, cstride, Idx, Lb, slots, prev,
                                       m1s);
    k_elem<<<1024, 256, 0, stream>>>(A, Xt, Lb, slots, step, prev, m1s, m2s);
  }

  k_out<<<dim3(G_ / 32, B_ / 32, C_), tb, 0, stream>>>(A, out, slots,
                                                       2 * NSTEP_);
}

// Round 4
// 582.375 us; speedup vs baseline: 1.9099x; 1.1199x over previous
//
#include <hip/hip_runtime.h>
#include <cstdint>
#include <cstddef>

// Problem constants (from reference setup_inputs)
#define C_ 4
#define B_ 128
#define G_ 2048
#define S_ 32
#define L_ 3
#define NSTEP_ 3
#define GAMMA_ 0.01f
#define INVG_ 100.0f
#define CG_ (C_ * G_)                  // 8192 (c,g) pairs
#define NTASK_ (CG_ * 2)               // wave-tasks per gather (2 b-halves)
#define NELEM_ ((size_t)C_ * G_ * B_)  // 1048576
#define PERC_ ((size_t)G_ * B_)        // 262144 (power of 2)

// Lazy-normalization slots: slots[k] = float-bits of global maxes (all > 0 so
// uint bit-compare == float compare). slot 0 stays 0 (scale 1 for step 0);
// step k writes m1 -> 2k+1, m2 -> 2k+2. Stream order = cross-kernel barrier.

__device__ __forceinline__ float slot_scale(const uint32_t* slots, int i) {
  const float m = __uint_as_float(
      __hip_atomic_load(slots + i, __ATOMIC_RELAXED, __HIP_MEMORY_SCOPE_AGENT));
  return (m > 1.0f) ? (1.0f / m) : 1.0f;
}

// ---------------------------------------------------------------------------
// k_init: Xt[g,b] = x[b,g] (tiled transpose, both sides coalesced)
// ---------------------------------------------------------------------------
__global__ __launch_bounds__(256) void k_init(const float* __restrict__ x,
                                              float* __restrict__ Xt) {
  __shared__ float tile[32][33];
  const int g0 = blockIdx.x * 32, b0 = blockIdx.y * 32;
  const int tx = threadIdx.x;
  for (int i = threadIdx.y; i < 32; i += 8)
    tile[i][tx] = x[(size_t)(b0 + i) * G_ + g0 + tx];  // tile[b][g]
  __syncthreads();
  for (int j = threadIdx.y; j < 32; j += 8)
    Xt[(size_t)(g0 + j) * B_ + b0 + tx] = tile[tx][j];
}

// ---------------------------------------------------------------------------
// k_gather: one wave per (cg, b-half) task, exactly one task per wave
// (grid 4096 x 256 = 16384 waves = NTASK_). Indices arrive via 2 coalesced
// loads then v_readlane (uniform SGPR lane index) -> row offsets are scalar ->
// row loads are saddr-form global_load with constant lane voffset: zero
// per-load VALU address math. S is processed in 4 chunks of 8 substitutions
// (24 staged loads, ~40 live VGPRs) with `#pragma unroll 1` so the compiler
// CANNOT merge chunks back into a 96-wide staging block (R3's spill failure:
// WRITE_SIZE 39MB of scratch traffic). Fixed-offset logsumexp (valuations
// bounded in [0,~1.05] -> exponent in [-50,55]): no max pass.
// ---------------------------------------------------------------------------
__global__ __launch_bounds__(256) void k_gather(
    const float* __restrict__ src, size_t cstride, const int* __restrict__ Idx,
    float* __restrict__ Lb, uint32_t* __restrict__ slots, int prev_slot,
    int out_slot) {
  __shared__ uint32_t smax;
  if (threadIdx.x == 0) smax = 0u;
  __syncthreads();
  const int lane = threadIdx.x & 63;
  const int wid = threadIdx.x >> 6;
  const float sc = slot_scale(slots, prev_slot);
  const float s3I = sc * sc * sc * INVG_;  // fold scale^3 into exp argument

  const int task = blockIdx.x * 4 + wid;
  const int cg = task >> 1;
  const int half = task & 1;
  const int c = cg >> 11;  // cg / G_
  const int* ip = Idx + (size_t)cg * (S_ * L_);
  const int i0 = ip[lane];              // k = 0..63
  const int i1 = ip[64 + (lane & 31)];  // k = 64..95
  const float* base = src + (size_t)c * cstride + half * 64 + lane;

  float acc0 = 0.0f, acc1 = 0.0f;
#pragma unroll 1
  for (int ch = 0; ch < 4; ++ch) {
    float v[24];
#pragma unroll
    for (int j = 0; j < 24; ++j) {
      const int k = ch * 24 + j;  // uniform (SGPR) lane selector
      const int e = (k < 64) ? __builtin_amdgcn_readlane(i0, k)
                             : __builtin_amdgcn_readlane(i1, k - 64);
      v[j] = base[(size_t)e * B_];
    }
#pragma unroll
    for (int s = 0; s < 8; ++s) {
      const float p = (v[3 * s] * v[3 * s + 1]) * v[3 * s + 2];
      const float e = __expf(fmaf(p, s3I, -50.0f));
      if (s & 1) acc1 += e; else acc0 += e;  // split dependency chain
    }
  }
  const float lse = 0.5f + GAMMA_ * __logf(acc0 + acc1);
  Lb[(size_t)cg * B_ + half * 64 + lane] = lse;

  atomicMax(&smax, __float_as_uint(lse));
  __syncthreads();
  if (threadIdx.x == 0) atomicMax(slots + out_slot, smax);
}

// ---------------------------------------------------------------------------
// k_elem: A = softor2(R_prev * sprev, lse1 * s1), float4-vectorized,
// with global-max side computation.
// ---------------------------------------------------------------------------
__global__ __launch_bounds__(256) void k_elem(float* __restrict__ A,
                                              const float* __restrict__ Xt,
                                              const float* __restrict__ Lb,
                                              uint32_t* __restrict__ slots,
                                              int step, int prev_slot,
                                              int m1_slot, int out_slot) {
  __shared__ uint32_t smax;
  if (threadIdx.x == 0) smax = 0u;
  __syncthreads();
  const float spI = slot_scale(slots, prev_slot) * INVG_;
  const float s1I = slot_scale(slots, m1_slot) * INVG_;
  float tmax = 0.0f;
  const size_t n4 = NELEM_ / 4;
  const size_t stride = (size_t)gridDim.x * blockDim.x;
  float4* A4 = (float4*)A;
  const float4* X4 = (const float4*)Xt;
  const float4* L4 = (const float4*)Lb;
  for (size_t i = (size_t)blockIdx.x * blockDim.x + threadIdx.x; i < n4;
       i += stride) {
    const float4 R = (step == 0) ? X4[i & (PERC_ / 4 - 1)] : A4[i];
    const float4 ce = L4[i];
    float4 o;
    o.x = 0.5f + GAMMA_ * __logf(__expf(fmaf(R.x, spI, -50.0f)) +
                                 __expf(fmaf(ce.x, s1I, -50.0f)));
    o.y = 0.5f + GAMMA_ * __logf(__expf(fmaf(R.y, spI, -50.0f)) +
                                 __expf(fmaf(ce.y, s1I, -50.0f)));
    o.z = 0.5f + GAMMA_ * __logf(__expf(fmaf(R.z, spI, -50.0f)) +
                                 __expf(fmaf(ce.z, s1I, -50.0f)));
    o.w = 0.5f + GAMMA_ * __logf(__expf(fmaf(R.w, spI, -50.0f)) +
                                 __expf(fmaf(ce.w, s1I, -50.0f)));
    A4[i] = o;
    tmax = fmaxf(fmaxf(fmaxf(o.x, o.y), fmaxf(o.z, o.w)), tmax);
  }
  atomicMax(&smax, __float_as_uint(tmax));
  __syncthreads();
  if (threadIdx.x == 0) atomicMax(slots + out_slot, smax);
}

// ---------------------------------------------------------------------------
// k_out: out[c,b,g] = A[c,g,b] * final_scale (tiled transpose back)
// ---------------------------------------------------------------------------
__global__ __launch_bounds__(256) void k_out(const float* __restrict__ A,
                                             float* __restrict__ out,
                                             const uint32_t* __restrict__ slots,
                                             int mslot) {
  __shared__ float tile[32][33];
  const float sc = slot_scale(slots, mslot);
  const int g0 = blockIdx.x * 32, b0 = blockIdx.y * 32, c = blockIdx.z;
  const int tx = threadIdx.x;
  for (int j = threadIdx.y; j < 32; j += 8)
    tile[j][tx] = A[((size_t)c * G_ + g0 + j) * B_ + b0 + tx];  // tile[g][b]
  __syncthreads();
  for (int i = threadIdx.y; i < 32; i += 8)
    out[((size_t)c * B_ + b0 + i) * G_ + g0 + tx] = tile[tx][i] * sc;
}

extern "C" void kernel_launch(void* const* d_in, const int* in_sizes, int n_in,
                              void* d_out, int out_size, void* d_ws,
                              size_t ws_size, hipStream_t stream) {
  const float* x = (const float*)d_in[0];  // [B,G]
  const int* Idx = (const int*)d_in[1];    // [C,G,S,L]
  float* out = (float*)d_out;              // [C,B,G]

  char* ws = (char*)d_ws;
  uint32_t* slots = (uint32_t*)ws;                          // 7 max slots
  float* Xt = (float*)(ws + 256);                           // [G,B]   1 MB
  float* A = (float*)(ws + 256 + PERC_ * 4);                // [C,G,B] 4 MB
  float* Lb = (float*)(ws + 256 + PERC_ * 4 + NELEM_ * 4);  // [C,G,B] 4 MB

  hipMemsetAsync(slots, 0, 8 * sizeof(uint32_t), stream);

  dim3 tb(32, 8);
  k_init<<<dim3(G_ / 32, B_ / 32), tb, 0, stream>>>(x, Xt);

  for (int step = 0; step < NSTEP_; ++step) {
    const int prev = 2 * step;  // slot 0 == 0 -> scale 1 for step 0
    const int m1s = 2 * step + 1;
    const int m2s = 2 * step + 2;
    const float* src = (step == 0) ? Xt : A;
    const size_t cstride = (step == 0) ? (size_t)0 : PERC_;
    k_gather<<<NTASK_ / 4, 256, 0, stream>>>(src, cstride, Idx, Lb, slots,
                                             prev, m1s);
    k_elem<<<1024, 256, 0, stream>>>(A, Xt, Lb, slots, step, prev, m1s, m2s);
  }

  k_out<<<dim3(G_ / 32, B_ / 32, C_), tb, 0, stream>>>(A, out, slots,
                                                       2 * NSTEP_);
}

// Round 5
// 578.052 us; speedup vs baseline: 1.9242x; 1.0075x over previous
//
#include <hip/hip_runtime.h>
#include <cstdint>
#include <cstddef>

// Problem constants (from reference setup_inputs)
#define C_ 4
#define B_ 128
#define G_ 2048
#define S_ 32
#define L_ 3
#define NSTEP_ 3
#define GAMMA_ 0.01f
#define INVG_ 100.0f
#define CG_ (C_ * G_)                  // 8192 (c,g) pairs
#define NELEM_ ((size_t)C_ * G_ * B_)  // 1048576
#define PERC_ ((size_t)G_ * B_)        // 262144 (power of 2)

// Lazy-normalization slots: slots[k] = float-bits of global maxes (all > 0 so
// uint bit-compare == float compare). slot 0 stays 0 (scale 1 for step 0);
// step k writes m1 -> 2k+1, m2 -> 2k+2. Stream order = cross-kernel barrier.

__device__ __forceinline__ float slot_scale(const uint32_t* slots, int i) {
  const float m = __uint_as_float(
      __hip_atomic_load(slots + i, __ATOMIC_RELAXED, __HIP_MEMORY_SCOPE_AGENT));
  return (m > 1.0f) ? (1.0f / m) : 1.0f;
}

// ---------------------------------------------------------------------------
// k_init: Xt[g,b] = x[b,g] (tiled transpose, both sides coalesced)
// ---------------------------------------------------------------------------
__global__ __launch_bounds__(256) void k_init(const float* __restrict__ x,
                                              float* __restrict__ Xt) {
  __shared__ float tile[32][33];
  const int g0 = blockIdx.x * 32, b0 = blockIdx.y * 32;
  const int tx = threadIdx.x;
  for (int i = threadIdx.y; i < 32; i += 8)
    tile[i][tx] = x[(size_t)(b0 + i) * G_ + g0 + tx];  // tile[b][g]
  __syncthreads();
  for (int j = threadIdx.y; j < 32; j += 8)
    Xt[(size_t)(g0 + j) * B_ + b0 + tx] = tile[tx][j];
}

// ---------------------------------------------------------------------------
// k_gather: R1's proven structure, 4x the waves. One block (128 thr = 2
// waves) per cg; tid IS the b index. Indices staged once to LDS (broadcast
// reads are conflict-free); per-lane VGPR address math (v_lshl_add_u64);
// body[32] product staging keeps ~40 VGPRs live, which is what lets the
// scheduler run loads ahead (R1: 9.1 TB/s effective vs 2.2 for the
// SGPR/chunked variants of R3/R4). Fixed-offset logsumexp (valuations in
// [0,~1.05] -> exponent in [-50,55]): no max pass, scale^3 folded into exp.
// ---------------------------------------------------------------------------
__global__ __launch_bounds__(128) void k_gather(
    const float* __restrict__ src, size_t cstride, const int* __restrict__ Idx,
    float* __restrict__ Lb, uint32_t* __restrict__ slots, int prev_slot,
    int out_slot) {
  __shared__ int sidx[S_ * L_];
  __shared__ uint32_t smax;
  const int tid = threadIdx.x;
  const int cg = blockIdx.x;
  const int c = cg >> 11;  // cg / G_
  if (tid == 0) smax = 0u;
  if (tid < S_ * L_) sidx[tid] = Idx[(size_t)cg * (S_ * L_) + tid];
  const float sc = slot_scale(slots, prev_slot);
  const float s3I = sc * sc * sc * INVG_;  // fold scale^3 into exp argument
  __syncthreads();

  const float* base = src + (size_t)c * cstride + tid;
  float body[S_];
#pragma unroll
  for (int s = 0; s < S_; ++s) {
    const float v0 = base[(size_t)sidx[3 * s + 0] * B_];
    const float v1 = base[(size_t)sidx[3 * s + 1] * B_];
    const float v2 = base[(size_t)sidx[3 * s + 2] * B_];
    body[s] = (v0 * v1) * v2;
  }
  float acc0 = 0.0f, acc1 = 0.0f;
#pragma unroll
  for (int s = 0; s < S_; ++s) {
    const float e = __expf(fmaf(body[s], s3I, -50.0f));
    if (s & 1) acc1 += e; else acc0 += e;  // split dependency chain
  }
  const float lse = 0.5f + GAMMA_ * __logf(acc0 + acc1);
  Lb[(size_t)cg * B_ + tid] = lse;

  atomicMax(&smax, __float_as_uint(lse));
  __syncthreads();
  if (tid == 0) atomicMax(slots + out_slot, smax);
}

// ---------------------------------------------------------------------------
// k_elem: A = softor2(R_prev * sprev, lse1 * s1), float4-vectorized,
// with global-max side computation.
// ---------------------------------------------------------------------------
__global__ __launch_bounds__(256) void k_elem(float* __restrict__ A,
                                              const float* __restrict__ Xt,
                                              const float* __restrict__ Lb,
                                              uint32_t* __restrict__ slots,
                                              int step, int prev_slot,
                                              int m1_slot, int out_slot) {
  __shared__ uint32_t smax;
  if (threadIdx.x == 0) smax = 0u;
  __syncthreads();
  const float spI = slot_scale(slots, prev_slot) * INVG_;
  const float s1I = slot_scale(slots, m1_slot) * INVG_;
  float tmax = 0.0f;
  const size_t n4 = NELEM_ / 4;
  const size_t stride = (size_t)gridDim.x * blockDim.x;
  float4* A4 = (float4*)A;
  const float4* X4 = (const float4*)Xt;
  const float4* L4 = (const float4*)Lb;
  for (size_t i = (size_t)blockIdx.x * blockDim.x + threadIdx.x; i < n4;
       i += stride) {
    const float4 R = (step == 0) ? X4[i & (PERC_ / 4 - 1)] : A4[i];
    const float4 ce = L4[i];
    float4 o;
    o.x = 0.5f + GAMMA_ * __logf(__expf(fmaf(R.x, spI, -50.0f)) +
                                 __expf(fmaf(ce.x, s1I, -50.0f)));
    o.y = 0.5f + GAMMA_ * __logf(__expf(fmaf(R.y, spI, -50.0f)) +
                                 __expf(fmaf(ce.y, s1I, -50.0f)));
    o.z = 0.5f + GAMMA_ * __logf(__expf(fmaf(R.z, spI, -50.0f)) +
                                 __expf(fmaf(ce.z, s1I, -50.0f)));
    o.w = 0.5f + GAMMA_ * __logf(__expf(fmaf(R.w, spI, -50.0f)) +
                                 __expf(fmaf(ce.w, s1I, -50.0f)));
    A4[i] = o;
    tmax = fmaxf(fmaxf(fmaxf(o.x, o.y), fmaxf(o.z, o.w)), tmax);
  }
  atomicMax(&smax, __float_as_uint(tmax));
  __syncthreads();
  if (threadIdx.x == 0) atomicMax(slots + out_slot, smax);
}

// ---------------------------------------------------------------------------
// k_out: out[c,b,g] = A[c,g,b] * final_scale (tiled transpose back)
// ---------------------------------------------------------------------------
__global__ __launch_bounds__(256) void k_out(const float* __restrict__ A,
                                             float* __restrict__ out,
                                             const uint32_t* __restrict__ slots,
                                             int mslot) {
  __shared__ float tile[32][33];
  const float sc = slot_scale(slots, mslot);
  const int g0 = blockIdx.x * 32, b0 = blockIdx.y * 32, c = blockIdx.z;
  const int tx = threadIdx.x;
  for (int j = threadIdx.y; j < 32; j += 8)
    tile[j][tx] = A[((size_t)c * G_ + g0 + j) * B_ + b0 + tx];  // tile[g][b]
  __syncthreads();
  for (int i = threadIdx.y; i < 32; i += 8)
    out[((size_t)c * B_ + b0 + i) * G_ + g0 + tx] = tile[tx][i] * sc;
}

extern "C" void kernel_launch(void* const* d_in, const int* in_sizes, int n_in,
                              void* d_out, int out_size, void* d_ws,
                              size_t ws_size, hipStream_t stream) {
  const float* x = (const float*)d_in[0];  // [B,G]
  const int* Idx = (const int*)d_in[1];    // [C,G,S,L]
  float* out = (float*)d_out;              // [C,B,G]

  char* ws = (char*)d_ws;
  uint32_t* slots = (uint32_t*)ws;                          // 7 max slots
  float* Xt = (float*)(ws + 256);                           // [G,B]   1 MB
  float* A = (float*)(ws + 256 + PERC_ * 4);                // [C,G,B] 4 MB
  float* Lb = (float*)(ws + 256 + PERC_ * 4 + NELEM_ * 4);  // [C,G,B] 4 MB

  hipMemsetAsync(slots, 0, 8 * sizeof(uint32_t), stream);

  dim3 tb(32, 8);
  k_init<<<dim3(G_ / 32, B_ / 32), tb, 0, stream>>>(x, Xt);

  for (int step = 0; step < NSTEP_; ++step) {
    const int prev = 2 * step;  // slot 0 == 0 -> scale 1 for step 0
    const int m1s = 2 * step + 1;
    const int m2s = 2 * step + 2;
    const float* src = (step == 0) ? Xt : A;
    const size_t cstride = (step == 0) ? (size_t)0 : PERC_;
    k_gather<<<CG_, 128, 0, stream>>>(src, cstride, Idx, Lb, slots, prev,
                                      m1s);
    k_elem<<<1024, 256, 0, stream>>>(A, Xt, Lb, slots, step, prev, m1s, m2s);
  }

  k_out<<<dim3(G_ / 32, B_ / 32, C_), tb, 0, stream>>>(A, out, slots,
                                                       2 * NSTEP_);
}